// Round 9
// baseline (304.971 us; speedup 1.0000x reference)
//
#include <hip/hip_runtime.h>
#include <hip/hip_bf16.h>

// Problem constants
#define B_   8
#define NQ_  2048
#define NKV_ 2048
#define DQ_  512
#define DIN_ 512

using f32x4  = __attribute__((ext_vector_type(4))) float;
using f32x16 = __attribute__((ext_vector_type(16))) float;
using bf16x4 = __attribute__((ext_vector_type(4))) __bf16;
using bf16x8 = __attribute__((ext_vector_type(8))) __bf16;

__device__ __forceinline__ f32x4 mfma16(bf16x8 a, bf16x8 b, f32x4 c) {
  return __builtin_amdgcn_mfma_f32_16x16x32_bf16(a, b, c, 0, 0, 0);
}
__device__ __forceinline__ f32x16 mfma32(bf16x8 a, bf16x8 b, f32x16 c) {
  return __builtin_amdgcn_mfma_f32_32x32x16_bf16(a, b, c, 0, 0, 0);
}

// async global->LDS, 16B per lane. LDS dest is wave-uniform base (+lane*16 in HW).
__device__ __forceinline__ void gload_lds16(const __bf16* g, __bf16* l) {
  __builtin_amdgcn_global_load_lds(
      (const __attribute__((address_space(1))) void*)g,
      (__attribute__((address_space(3))) void*)l, 16, 0, 0);
}

// bijective XCD-aware remap (nwg % 8 == 0)
__device__ __forceinline__ int xcd_swz(int bid, int nwg) {
  const int c = nwg >> 3;
  return (bid & 7) * c + (bid >> 3);
}

// ---------------------------------------------------------------------------
// Projection GEMM: C[m,n] = sum_k A[m,k]*B[n,k] + bias[n] (+ key), fp32 in,
// SPLIT bf16 hi/lo out. 3-product split accumulation (hh+hl+lh).
// ---------------------------------------------------------------------------
template<int EPI>
__global__ __launch_bounds__(256, 2)
void proj_gemm(const float* __restrict__ A, const float* __restrict__ Bm,
               __bf16* __restrict__ Ch, __bf16* __restrict__ Cl,
               const float* __restrict__ bias, const float* __restrict__ keyp)
{
  constexpr int PAD = 8;
  __shared__ __bf16 Ah[128][64 + PAD];
  __shared__ __bf16 Al[128][64 + PAD];
  __shared__ __bf16 Bh[128][64 + PAD];
  __shared__ __bf16 Bl[128][64 + PAD];

  const int tid  = threadIdx.x;
  const int lane = tid & 63;
  const int w    = tid >> 6;
  const int wr   = w >> 1;
  const int wc   = w & 1;
  const int brow = blockIdx.y * 128;
  const int bcol = blockIdx.x * 128;

  const float* Ag = A  + (size_t)brow * DQ_;
  const float* Bg = Bm + (size_t)bcol * DQ_;

  f32x4 acc[4][4] = {};

  const int sr = tid >> 4;
  const int sc = (tid & 15) * 4;

  float4 pa[8], pb[8];
#pragma unroll
  for (int p = 0; p < 8; ++p) {
    pa[p] = *(const float4*)(Ag + (size_t)(p * 16 + sr) * DQ_ + sc);
    pb[p] = *(const float4*)(Bg + (size_t)(p * 16 + sr) * DQ_ + sc);
  }

  for (int k0 = 0; k0 < DQ_; k0 += 64) {
    __syncthreads();
#pragma unroll
    for (int p = 0; p < 8; ++p) {
      const int r = p * 16 + sr;
      const float vva[4] = {pa[p].x, pa[p].y, pa[p].z, pa[p].w};
      const float vvb[4] = {pb[p].x, pb[p].y, pb[p].z, pb[p].w};
      bf16x4 ha, la, hb, lb;
#pragma unroll
      for (int j = 0; j < 4; ++j) {
        const __bf16 hba = (__bf16)vva[j];
        ha[j] = hba; la[j] = (__bf16)(vva[j] - (float)hba);
        const __bf16 hbb = (__bf16)vvb[j];
        hb[j] = hbb; lb[j] = (__bf16)(vvb[j] - (float)hbb);
      }
      *(bf16x4*)&Ah[r][sc] = ha;
      *(bf16x4*)&Al[r][sc] = la;
      *(bf16x4*)&Bh[r][sc] = hb;
      *(bf16x4*)&Bl[r][sc] = lb;
    }
    if (k0 + 64 < DQ_) {
#pragma unroll
      for (int p = 0; p < 8; ++p) {
        pa[p] = *(const float4*)(Ag + (size_t)(p * 16 + sr) * DQ_ + k0 + 64 + sc);
        pb[p] = *(const float4*)(Bg + (size_t)(p * 16 + sr) * DQ_ + k0 + 64 + sc);
      }
    }
    __syncthreads();
#pragma unroll
    for (int kk = 0; kk < 2; ++kk) {
      const int fr = lane & 15;
      const int fc = kk * 32 + (lane >> 4) * 8;
      bf16x8 ah[4], al[4], bh[4], bl[4];
#pragma unroll
      for (int m = 0; m < 4; ++m) {
        ah[m] = *(const bf16x8*)&Ah[wr * 64 + m * 16 + fr][fc];
        al[m] = *(const bf16x8*)&Al[wr * 64 + m * 16 + fr][fc];
      }
#pragma unroll
      for (int n = 0; n < 4; ++n) {
        bh[n] = *(const bf16x8*)&Bh[wc * 64 + n * 16 + fr][fc];
        bl[n] = *(const bf16x8*)&Bl[wc * 64 + n * 16 + fr][fc];
      }
#pragma unroll
      for (int m = 0; m < 4; ++m)
#pragma unroll
        for (int n = 0; n < 4; ++n) {
          acc[m][n] = mfma16(ah[m], bh[n], acc[m][n]);
          acc[m][n] = mfma16(ah[m], bl[n], acc[m][n]);
          acc[m][n] = mfma16(al[m], bh[n], acc[m][n]);
        }
    }
  }

#pragma unroll
  for (int m = 0; m < 4; ++m)
#pragma unroll
    for (int n = 0; n < 4; ++n)
#pragma unroll
      for (int r = 0; r < 4; ++r) {
        const int row_g = brow + wr * 64 + m * 16 + (lane >> 4) * 4 + r;
        const int col_g = bcol + wc * 64 + n * 16 + (lane & 15);
        float vv = acc[m][n][r] + bias[col_g];
        if (EPI == 2) vv += keyp[(size_t)(row_g & (NKV_ - 1)) * DQ_ + col_g];
        const __bf16 h = (__bf16)vv;
        Ch[(size_t)row_g * DQ_ + col_g] = h;
        Cl[(size_t)row_g * DQ_ + col_g] = (__bf16)(vv - (float)h);
      }
}

// ---------------------------------------------------------------------------
// Score GEMM, 256x256 tile, 512 threads (8 waves), wave-owned 128x64 tiles,
// 32x32x16 MFMA (2x FLOP/instr vs 16x16x32, same LDS bytes).
// K-chunk = 32 real K, double-buffered parity LDS (128 KiB). Per chunk/wave:
// 24 ds_read_b128, 48 MFMA (4mi x 2ni x 2steps x 3 split-products).
// A/B frag: row=lane&31, k=(lane>>5)*8+j. LDS row = [hi slots0-3|lo slots4-7]
// of 8 bf16, phys slot = logical ^ (row&7). One vmcnt(0)+barrier per chunk.
// C/D: col=lane&31, row=(r&3)+8*(r>>2)+4*(lane>>5).
// ---------------------------------------------------------------------------
__global__ __launch_bounds__(512, 2)
void score_gemm(const __bf16* __restrict__ qph, const __bf16* __restrict__ qpl,
                const __bf16* __restrict__ kmh, const __bf16* __restrict__ kml,
                float* __restrict__ attn)
{
  extern __shared__ __bf16 lds[];
  __bf16* ABuf = lds;            // [2 parity][256 rows][64]
  __bf16* BBuf = lds + 32768;

  const int swz  = xcd_swz(blockIdx.x, gridDim.x);   // 512 blocks
  const int bx   = swz & 7;           // NKV block (256)
  const int by   = (swz >> 3) & 7;    // NQ block (256)
  const int b    = swz >> 6;          // batch

  const int t    = threadIdx.x;       // 0..511
  const int lane = t & 63;
  const int w    = t >> 6;            // 0..7
  const int wr   = w >> 2;            // 0..1 (M: rows wr*128..+128)
  const int wcn  = w & 3;             // 0..3 (N: cols wcn*64..+64)
  const int brow = by * 256;
  const int bcol = bx * 256;
  const int fr   = lane & 31;         // frag row (32-row frags)
  const int half = lane >> 5;         // k-half within a K=16 step

  // staging map (proven): thread t covers rows srow + j*64, phys slot t&7.
  const int srow = t >> 3;                  // 0..63
  const int sig  = (t & 7) ^ (srow & 7);    // logical slot fetched
  const __bf16* aGh = qph + ((size_t)b * NQ_  + brow + srow) * DQ_ + (sig & 3) * 8;
  const __bf16* aGl = qpl + ((size_t)b * NQ_  + brow + srow) * DQ_ + (sig & 3) * 8;
  const __bf16* bGh = kmh + ((size_t)b * NKV_ + bcol + srow) * DQ_ + (sig & 3) * 8;
  const __bf16* bGl = kml + ((size_t)b * NKV_ + bcol + srow) * DQ_ + (sig & 3) * 8;

#define STAGE_A(kc) do { \
    const __bf16* s_ = (sig < 4 ? aGh : aGl) + (kc) * 32; \
    __bf16* d_ = ABuf + ((kc) & 1) * 16384 + w * 512; \
    _Pragma("unroll") for (int j_ = 0; j_ < 4; ++j_) \
      gload_lds16(s_ + (size_t)j_ * 64 * DQ_, d_ + j_ * 4096); } while (0)
#define STAGE_B(kc) do { \
    const __bf16* s_ = (sig < 4 ? bGh : bGl) + (kc) * 32; \
    __bf16* d_ = BBuf + ((kc) & 1) * 16384 + w * 512; \
    _Pragma("unroll") for (int j_ = 0; j_ < 4; ++j_) \
      gload_lds16(s_ + (size_t)j_ * 64 * DQ_, d_ + j_ * 4096); } while (0)

  f32x16 acc[4][2] = {};   // wave-owned 128x64: 4 m-frags x 2 n-frags (32x32)

  // prologue: stage chunk 0, drain, barrier.
  STAGE_A(0); STAGE_B(0);
  asm volatile("s_waitcnt vmcnt(0)\n\ts_barrier" ::: "memory");

  for (int c = 0; c < 16; ++c) {
    if (c + 1 < 16) { STAGE_A(c + 1); STAGE_B(c + 1); }

    const __bf16* Ab = ABuf + (c & 1) * 16384;
    const __bf16* Bb = BBuf + (c & 1) * 16384;

#pragma unroll
    for (int s = 0; s < 2; ++s) {                    // K=16 steps
      const int oH = ((s * 2 + half)     ^ (fr & 7)) * 8;
      const int oL = ((4 + s * 2 + half) ^ (fr & 7)) * 8;

      bf16x8 bh[2], bl[2];
#pragma unroll
      for (int ni = 0; ni < 2; ++ni) {
        const __bf16* p = Bb + (wcn * 64 + ni * 32 + fr) * 64;
        bh[ni] = *(const bf16x8*)(p + oH);
        bl[ni] = *(const bf16x8*)(p + oL);
      }
      __builtin_amdgcn_s_setprio(1);
#pragma unroll
      for (int mi = 0; mi < 4; ++mi) {
        const __bf16* p = Ab + (wr * 128 + mi * 32 + fr) * 64;
        const bf16x8 ah = *(const bf16x8*)(p + oH);
        const bf16x8 al = *(const bf16x8*)(p + oL);
#pragma unroll
        for (int ni = 0; ni < 2; ++ni) {
          f32x16 cc = acc[mi][ni];
          cc = mfma32(ah, bh[ni], cc);
          cc = mfma32(ah, bl[ni], cc);
          cc = mfma32(al, bh[ni], cc);
          acc[mi][ni] = cc;
        }
      }
      __builtin_amdgcn_s_setprio(0);
    }

    if (c + 1 < 16)
      asm volatile("s_waitcnt vmcnt(0)\n\ts_barrier" ::: "memory");
  }
#undef STAGE_A
#undef STAGE_B

  float* Cg = attn + (size_t)b * NQ_ * NKV_;
#pragma unroll
  for (int mi = 0; mi < 4; ++mi)
#pragma unroll
    for (int ni = 0; ni < 2; ++ni)
#pragma unroll
      for (int r = 0; r < 16; ++r) {
        const int row_g = brow + wr * 128 + mi * 32 + (r & 3) + 8 * (r >> 2) + 4 * half;
        const int col_g = bcol + wcn * 64 + ni * 32 + fr;
        Cg[(size_t)row_g * NKV_ + col_g] = acc[mi][ni][r];
      }
}

// ---------------------------------------------------------------------------
// PV GEMM: out[b,q,n] = sum_j attnb[b,q,j] * xT[b,n,j]. Both operands bf16,
// 32x32x16 MFMA, wave tile 64x64 (2x2 wave grid on 128^2 block tile).
// Double-buffered 2-phase: stage chunk ks+1 during compute of ks; single
// counted vmcnt(0) AFTER the MFMA cluster. 64 KB LDS -> 2 blocks/CU.
// ---------------------------------------------------------------------------
__global__ __launch_bounds__(256, 2)
void pv_gemm(const __bf16* __restrict__ attnb, const __bf16* __restrict__ xT,
             float* __restrict__ out)
{
  __shared__ __bf16 At[2][128 * 64];
  __shared__ __bf16 Bt[2][128 * 64];

  const int swz  = xcd_swz(blockIdx.x, gridDim.x);
  const int bx   = swz & 3;           // DIN block
  const int by   = (swz >> 2) & 15;   // NQ block
  const int b    = swz >> 6;          // batch

  const int t    = threadIdx.x;
  const int lane = t & 63;
  const int w    = t >> 6;
  const int wr   = w >> 1;
  const int wc   = w & 1;
  const int brow = by * 128;   // q rows
  const int bcol = bx * 128;   // din cols
  const int fr   = lane & 31;
  const int half = lane >> 5;

  const int srow  = t >> 3;
  const int sslot = t & 7;
  const int sig   = sslot ^ (srow & 7);
  const __bf16* aG = attnb + ((size_t)b * NQ_ + brow + srow) * NKV_ + sig * 8;
  const __bf16* bG = xT + (size_t)b * DIN_ * NKV_ + (size_t)(bcol + srow) * NKV_ + sig * 8;

  f32x16 acc[2][2] = {};

#define PV_STAGE(ks, buf) do { \
    const __bf16* a_ = aG + (size_t)(ks) * 64; \
    const __bf16* b_ = bG + (size_t)(ks) * 64; \
    __bf16* al_ = At[buf] + w * 512; \
    __bf16* bl_ = Bt[buf] + w * 512; \
    _Pragma("unroll") for (int i = 0; i < 4; ++i) { \
      gload_lds16(a_ + (size_t)i * 32 * NKV_, al_ + i * 2048); \
      gload_lds16(b_ + (size_t)i * 32 * NKV_, bl_ + i * 2048); } } while (0)

  // prologue: stage chunk 0, drain, barrier.
  PV_STAGE(0, 0);
  asm volatile("s_waitcnt vmcnt(0)\n\ts_barrier" ::: "memory");

  for (int ks = 0; ks < NKV_ / 64; ++ks) {
    const int cur = ks & 1;
    if (ks + 1 < NKV_ / 64) PV_STAGE(ks + 1, cur ^ 1);

    const __bf16* Ac = At[cur];
    const __bf16* Bc = Bt[cur];
#pragma unroll
    for (int s = 0; s < 4; ++s) {                  // K=16 steps over K=64
      const int oS = ((s * 2 + half) ^ (fr & 7)) * 8;
      bf16x8 bh[2];
#pragma unroll
      for (int ni = 0; ni < 2; ++ni)
        bh[ni] = *(const bf16x8*)&Bc[(wc * 64 + ni * 32 + fr) * 64 + oS];
      __builtin_amdgcn_s_setprio(1);
#pragma unroll
      for (int mi = 0; mi < 2; ++mi) {
        const bf16x8 ah = *(const bf16x8*)&Ac[(wr * 64 + mi * 32 + fr) * 64 + oS];
#pragma unroll
        for (int ni = 0; ni < 2; ++ni)
          acc[mi][ni] = mfma32(ah, bh[ni], acc[mi][ni]);
      }
      __builtin_amdgcn_s_setprio(0);
    }
    asm volatile("s_waitcnt vmcnt(0)\n\ts_barrier" ::: "memory");
  }
#undef PV_STAGE

  float* Cg = out + (size_t)b * NQ_ * DIN_;
#pragma unroll
  for (int mi = 0; mi < 2; ++mi)
#pragma unroll
    for (int ni = 0; ni < 2; ++ni)
#pragma unroll
      for (int r = 0; r < 16; ++r) {
        const int row_g = brow + wr * 64 + mi * 32 + (r & 3) + 8 * (r >> 2) + 4 * half;
        const int col_g = bcol + wc * 64 + ni * 32 + fr;
        Cg[(size_t)row_g * DIN_ + col_g] = acc[mi][ni][r];
      }
}

// ---------------------------------------------------------------------------
// x [B, NKV, DIN] fp32 -> xT [B, DIN, NKV] bf16
// ---------------------------------------------------------------------------
__global__ void transpose_x(const float* __restrict__ x, __bf16* __restrict__ xT)
{
  __shared__ float tile[32][33];
  const int b  = blockIdx.z;
  const int j0 = blockIdx.x * 32;   // NKV index
  const int i0 = blockIdx.y * 32;   // DIN index
  const float* xs = x  + (size_t)b * NKV_ * DIN_;
  __bf16*      xd = xT + (size_t)b * DIN_ * NKV_;
  const int tx = threadIdx.x, ty = threadIdx.y;  // 32 x 8
#pragma unroll
  for (int p = 0; p < 32; p += 8)
    tile[ty + p][tx] = xs[(size_t)(j0 + ty + p) * DIN_ + i0 + tx];
  __syncthreads();
#pragma unroll
  for (int p = 0; p < 32; p += 8)
    xd[(size_t)(i0 + ty + p) * NKV_ + j0 + tx] = (__bf16)tile[tx][ty + p];
}

// ---------------------------------------------------------------------------
// In-place row softmax over attn [rows x 2048]; also writes bf16 copy.
// ---------------------------------------------------------------------------
__global__ void softmax_rows(float* __restrict__ attn, __bf16* __restrict__ attnb)
{
  const int lane = threadIdx.x & 63;
  const int wv   = threadIdx.x >> 6;
  const size_t row = (size_t)blockIdx.x * 4 + wv;
  float*  p  = attn  + row * NKV_;
  __bf16* pb = attnb + row * NKV_;

  float4 v[8];
  float mx = -1e30f;
#pragma unroll
  for (int i = 0; i < 8; ++i) {
    v[i] = *(const float4*)&p[i * 256 + lane * 4];
    mx = fmaxf(mx, fmaxf(fmaxf(v[i].x, v[i].y), fmaxf(v[i].z, v[i].w)));
  }
#pragma unroll
  for (int off = 32; off; off >>= 1) mx = fmaxf(mx, __shfl_xor(mx, off, 64));

  float sum = 0.f;
#pragma unroll
  for (int i = 0; i < 8; ++i) {
    v[i].x = expf(v[i].x - mx);
    v[i].y = expf(v[i].y - mx);
    v[i].z = expf(v[i].z - mx);
    v[i].w = expf(v[i].w - mx);
    sum += v[i].x + v[i].y + v[i].z + v[i].w;
  }
#pragma unroll
  for (int off = 32; off; off >>= 1) sum += __shfl_xor(sum, off, 64);

  const float inv = 1.0f / sum;
#pragma unroll
  for (int i = 0; i < 8; ++i) {
    v[i].x *= inv; v[i].y *= inv; v[i].z *= inv; v[i].w *= inv;
    *(float4*)&p[i * 256 + lane * 4] = v[i];
    bf16x4 hv;
    hv[0] = (__bf16)v[i].x; hv[1] = (__bf16)v[i].y;
    hv[2] = (__bf16)v[i].z; hv[3] = (__bf16)v[i].w;
    *(bf16x4*)&pb[i * 256 + lane * 4] = hv;
  }
}

// ---------------------------------------------------------------------------
extern "C" void kernel_launch(void* const* d_in, const int* in_sizes, int n_in,
                              void* d_out, int out_size, void* d_ws, size_t ws_size,
                              hipStream_t stream)
{
  (void)in_sizes; (void)n_in; (void)out_size; (void)ws_size;
  const float* query  = (const float*)d_in[0];  // [8, 2048, 512]
  const float* key    = (const float*)d_in[1];  // [2048, 512]
  const float* x      = (const float*)d_in[2];  // [8, 2048, 512]
  const float* W_proj = (const float*)d_in[3];  // [512, 512]
  const float* b_proj = (const float*)d_in[4];  // [512]
  const float* W_px   = (const float*)d_in[5];  // [512, 512]
  const float* b_px   = (const float*)d_in[6];  // [512]

  float* out  = (float*)d_out;                          // [8, 2048, 512]
  float* attn = out + (size_t)B_ * NQ_ * DIN_;          // [8, 2048, 2048]

  const size_t PQE = (size_t)B_ * NQ_ * DQ_;            // 8.39M elements
  __bf16* qph = (__bf16*)d_ws;
  __bf16* qpl = qph + PQE;
  __bf16* kmh = qpl + PQE;
  __bf16* kml = kmh + PQE;
  __bf16* xT  = kml + PQE;                              // [8, 512, 2048] bf16
  // after score_gemm, qp/km are dead: reuse their 4*PQE bf16 region (=67.1MB)
  // for the bf16 attn copy (8*2048*2048 = 4*PQE elements exactly).
  __bf16* attnb = qph;

  // allow 128 KiB dynamic LDS for score_gemm (idempotent, capture-safe)
  hipFuncSetAttribute((const void*)score_gemm,
                      hipFuncAttributeMaxDynamicSharedMemorySize, 131072);

  // x^T (bf16) for the PV GEMM B-operand
  transpose_x<<<dim3(NKV_ / 32, DIN_ / 32, B_), dim3(32, 8), 0, stream>>>(x, xT);

  // q_proj = query @ W_proj^T + b_proj  -> split bf16
  proj_gemm<1><<<dim3(DQ_ / 128, (B_ * NQ_) / 128, 1), 256, 0, stream>>>(
      query, W_proj, qph, qpl, b_proj, nullptr);

  // k = x @ W_px^T + b_px + key        -> split bf16
  proj_gemm<2><<<dim3(DQ_ / 128, (B_ * NQ_) / 128, 1), 256, 0, stream>>>(
      x, W_px, kmh, kml, b_px, key);

  // raw scores into attn region of d_out (256^2 tiles, XCD-swizzled)
  score_gemm<<<(NKV_ / 256) * (NQ_ / 256) * B_, 512, 131072, stream>>>(
      qph, qpl, kmh, kml, attn);

  // softmax rows in place + bf16 copy into ws
  softmax_rows<<<(B_ * NQ_) / 4, 256, 0, stream>>>(attn, attnb);

  // out[b] = attn[b] @ x[b]  (1D grid, XCD-swizzled)
  pv_gemm<<<(DIN_ / 128) * (NQ_ / 128) * B_, 256, 0, stream>>>(attnb, xT, out);
}

// Round 10
// 303.981 us; speedup vs baseline: 1.0033x; 1.0033x over previous
//
#include <hip/hip_runtime.h>
#include <hip/hip_bf16.h>

// Problem constants
#define B_   8
#define NQ_  2048
#define NKV_ 2048
#define DQ_  512
#define DIN_ 512

using f32x4  = __attribute__((ext_vector_type(4))) float;
using f32x16 = __attribute__((ext_vector_type(16))) float;
using bf16x4 = __attribute__((ext_vector_type(4))) __bf16;
using bf16x8 = __attribute__((ext_vector_type(8))) __bf16;

__device__ __forceinline__ f32x4 mfma16(bf16x8 a, bf16x8 b, f32x4 c) {
  return __builtin_amdgcn_mfma_f32_16x16x32_bf16(a, b, c, 0, 0, 0);
}
__device__ __forceinline__ f32x16 mfma32(bf16x8 a, bf16x8 b, f32x16 c) {
  return __builtin_amdgcn_mfma_f32_32x32x16_bf16(a, b, c, 0, 0, 0);
}

// async global->LDS, 16B per lane. LDS dest is wave-uniform base (+lane*16 in HW).
__device__ __forceinline__ void gload_lds16(const __bf16* g, __bf16* l) {
  __builtin_amdgcn_global_load_lds(
      (const __attribute__((address_space(1))) void*)g,
      (__attribute__((address_space(3))) void*)l, 16, 0, 0);
}

// bijective XCD-aware remap (nwg % 8 == 0)
__device__ __forceinline__ int xcd_swz(int bid, int nwg) {
  const int c = nwg >> 3;
  return (bid & 7) * c + (bid >> 3);
}

// ---------------------------------------------------------------------------
// Projection GEMM: C[m,n] = sum_k A[m,k]*B[n,k] + bias[n] (+ key), fp32 in,
// SPLIT bf16 hi/lo out. 3-product split accumulation (hh+hl+lh).
// ---------------------------------------------------------------------------
template<int EPI>
__global__ __launch_bounds__(256, 2)
void proj_gemm(const float* __restrict__ A, const float* __restrict__ Bm,
               __bf16* __restrict__ Ch, __bf16* __restrict__ Cl,
               const float* __restrict__ bias, const float* __restrict__ keyp)
{
  constexpr int PAD = 8;
  __shared__ __bf16 Ah[128][64 + PAD];
  __shared__ __bf16 Al[128][64 + PAD];
  __shared__ __bf16 Bh[128][64 + PAD];
  __shared__ __bf16 Bl[128][64 + PAD];

  const int tid  = threadIdx.x;
  const int lane = tid & 63;
  const int w    = tid >> 6;
  const int wr   = w >> 1;
  const int wc   = w & 1;
  const int brow = blockIdx.y * 128;
  const int bcol = blockIdx.x * 128;

  const float* Ag = A  + (size_t)brow * DQ_;
  const float* Bg = Bm + (size_t)bcol * DQ_;

  f32x4 acc[4][4] = {};

  const int sr = tid >> 4;
  const int sc = (tid & 15) * 4;

  float4 pa[8], pb[8];
#pragma unroll
  for (int p = 0; p < 8; ++p) {
    pa[p] = *(const float4*)(Ag + (size_t)(p * 16 + sr) * DQ_ + sc);
    pb[p] = *(const float4*)(Bg + (size_t)(p * 16 + sr) * DQ_ + sc);
  }

  for (int k0 = 0; k0 < DQ_; k0 += 64) {
    __syncthreads();
#pragma unroll
    for (int p = 0; p < 8; ++p) {
      const int r = p * 16 + sr;
      const float vva[4] = {pa[p].x, pa[p].y, pa[p].z, pa[p].w};
      const float vvb[4] = {pb[p].x, pb[p].y, pb[p].z, pb[p].w};
      bf16x4 ha, la, hb, lb;
#pragma unroll
      for (int j = 0; j < 4; ++j) {
        const __bf16 hba = (__bf16)vva[j];
        ha[j] = hba; la[j] = (__bf16)(vva[j] - (float)hba);
        const __bf16 hbb = (__bf16)vvb[j];
        hb[j] = hbb; lb[j] = (__bf16)(vvb[j] - (float)hbb);
      }
      *(bf16x4*)&Ah[r][sc] = ha;
      *(bf16x4*)&Al[r][sc] = la;
      *(bf16x4*)&Bh[r][sc] = hb;
      *(bf16x4*)&Bl[r][sc] = lb;
    }
    if (k0 + 64 < DQ_) {
#pragma unroll
      for (int p = 0; p < 8; ++p) {
        pa[p] = *(const float4*)(Ag + (size_t)(p * 16 + sr) * DQ_ + k0 + 64 + sc);
        pb[p] = *(const float4*)(Bg + (size_t)(p * 16 + sr) * DQ_ + k0 + 64 + sc);
      }
    }
    __syncthreads();
#pragma unroll
    for (int kk = 0; kk < 2; ++kk) {
      const int fr = lane & 15;
      const int fc = kk * 32 + (lane >> 4) * 8;
      bf16x8 ah[4], al[4], bh[4], bl[4];
#pragma unroll
      for (int m = 0; m < 4; ++m) {
        ah[m] = *(const bf16x8*)&Ah[wr * 64 + m * 16 + fr][fc];
        al[m] = *(const bf16x8*)&Al[wr * 64 + m * 16 + fr][fc];
      }
#pragma unroll
      for (int n = 0; n < 4; ++n) {
        bh[n] = *(const bf16x8*)&Bh[wc * 64 + n * 16 + fr][fc];
        bl[n] = *(const bf16x8*)&Bl[wc * 64 + n * 16 + fr][fc];
      }
#pragma unroll
      for (int m = 0; m < 4; ++m)
#pragma unroll
        for (int n = 0; n < 4; ++n) {
          acc[m][n] = mfma16(ah[m], bh[n], acc[m][n]);
          acc[m][n] = mfma16(ah[m], bl[n], acc[m][n]);
          acc[m][n] = mfma16(al[m], bh[n], acc[m][n]);
        }
    }
  }

#pragma unroll
  for (int m = 0; m < 4; ++m)
#pragma unroll
    for (int n = 0; n < 4; ++n)
#pragma unroll
      for (int r = 0; r < 4; ++r) {
        const int row_g = brow + wr * 64 + m * 16 + (lane >> 4) * 4 + r;
        const int col_g = bcol + wc * 64 + n * 16 + (lane & 15);
        float vv = acc[m][n][r] + bias[col_g];
        if (EPI == 2) vv += keyp[(size_t)(row_g & (NKV_ - 1)) * DQ_ + col_g];
        const __bf16 h = (__bf16)vv;
        Ch[(size_t)row_g * DQ_ + col_g] = h;
        Cl[(size_t)row_g * DQ_ + col_g] = (__bf16)(vv - (float)h);
      }
}

// ---------------------------------------------------------------------------
// Score GEMM, 256x256 tile, 512 threads (8 waves), wave-owned 128x64 tiles,
// 32x32x16 MFMA. Slot swizzle WIDENED to kill stride-8 lane aliasing:
// phys = logical ^ g(row), g(row) = (row&7) ^ (((row>>3)&1)<<2).
// (row>>3)&1 is invariant under the +64-row staging stride, so g is a
// per-thread constant on both the staging (sig) and read (gg) sides.
// K-chunk = 32 real K, double-buffered parity LDS (128 KiB), one
// vmcnt(0)+barrier per chunk. 24 ds_read_b128 + 48 MFMA per chunk per wave.
// ---------------------------------------------------------------------------
__global__ __launch_bounds__(512, 2)
void score_gemm(const __bf16* __restrict__ qph, const __bf16* __restrict__ qpl,
                const __bf16* __restrict__ kmh, const __bf16* __restrict__ kml,
                float* __restrict__ attn)
{
  extern __shared__ __bf16 lds[];
  __bf16* ABuf = lds;            // [2 parity][256 rows][64]
  __bf16* BBuf = lds + 32768;

  const int swz  = xcd_swz(blockIdx.x, gridDim.x);   // 512 blocks
  const int bx   = swz & 7;           // NKV block (256)
  const int by   = (swz >> 3) & 7;    // NQ block (256)
  const int b    = swz >> 6;          // batch

  const int t    = threadIdx.x;       // 0..511
  const int lane = t & 63;
  const int w    = t >> 6;            // 0..7
  const int wr   = w >> 2;            // 0..1 (M: rows wr*128..+128)
  const int wcn  = w & 3;             // 0..3 (N: cols wcn*64..+64)
  const int brow = by * 256;
  const int bcol = bx * 256;
  const int fr   = lane & 31;         // frag row (32-row frags)
  const int half = lane >> 5;         // k-half within a K=16 step
  const int gg   = (fr & 7) ^ (((fr >> 3) & 1) << 2);  // read-side swizzle

  // staging map: thread t -> row srow=t>>3 (+j*64), phys slot t&7,
  // logical sig = phys ^ g(srow), g = (srow&7) ^ (((srow>>3)&1)<<2).
  const int srow = t >> 3;                  // 0..63
  const int sig  = (t & 7) ^ ((t >> 3) & 7) ^ (((t >> 6) & 1) << 2);
  const __bf16* aGh = qph + ((size_t)b * NQ_  + brow + srow) * DQ_ + (sig & 3) * 8;
  const __bf16* aGl = qpl + ((size_t)b * NQ_  + brow + srow) * DQ_ + (sig & 3) * 8;
  const __bf16* bGh = kmh + ((size_t)b * NKV_ + bcol + srow) * DQ_ + (sig & 3) * 8;
  const __bf16* bGl = kml + ((size_t)b * NKV_ + bcol + srow) * DQ_ + (sig & 3) * 8;

#define STAGE_A(kc) do { \
    const __bf16* s_ = (sig < 4 ? aGh : aGl) + (kc) * 32; \
    __bf16* d_ = ABuf + ((kc) & 1) * 16384 + w * 512; \
    _Pragma("unroll") for (int j_ = 0; j_ < 4; ++j_) \
      gload_lds16(s_ + (size_t)j_ * 64 * DQ_, d_ + j_ * 4096); } while (0)
#define STAGE_B(kc) do { \
    const __bf16* s_ = (sig < 4 ? bGh : bGl) + (kc) * 32; \
    __bf16* d_ = BBuf + ((kc) & 1) * 16384 + w * 512; \
    _Pragma("unroll") for (int j_ = 0; j_ < 4; ++j_) \
      gload_lds16(s_ + (size_t)j_ * 64 * DQ_, d_ + j_ * 4096); } while (0)

  f32x16 acc[4][2] = {};   // wave-owned 128x64: 4 m-frags x 2 n-frags (32x32)

  // prologue: stage chunk 0, drain, barrier.
  STAGE_A(0); STAGE_B(0);
  asm volatile("s_waitcnt vmcnt(0)\n\ts_barrier" ::: "memory");

  for (int c = 0; c < 16; ++c) {
    if (c + 1 < 16) { STAGE_A(c + 1); STAGE_B(c + 1); }

    const __bf16* Ab = ABuf + (c & 1) * 16384;
    const __bf16* Bb = BBuf + (c & 1) * 16384;

#pragma unroll
    for (int s = 0; s < 2; ++s) {                    // K=16 steps
      const int oH = ((s * 2 + half)     ^ gg) * 8;
      const int oL = ((4 + s * 2 + half) ^ gg) * 8;

      bf16x8 bh[2], bl[2];
#pragma unroll
      for (int ni = 0; ni < 2; ++ni) {
        const __bf16* p = Bb + (wcn * 64 + ni * 32 + fr) * 64;
        bh[ni] = *(const bf16x8*)(p + oH);
        bl[ni] = *(const bf16x8*)(p + oL);
      }
      __builtin_amdgcn_s_setprio(1);
#pragma unroll
      for (int mi = 0; mi < 4; ++mi) {
        const __bf16* p = Ab + (wr * 128 + mi * 32 + fr) * 64;
        const bf16x8 ah = *(const bf16x8*)(p + oH);
        const bf16x8 al = *(const bf16x8*)(p + oL);
#pragma unroll
        for (int ni = 0; ni < 2; ++ni) {
          f32x16 cc = acc[mi][ni];
          cc = mfma32(ah, bh[ni], cc);
          cc = mfma32(ah, bl[ni], cc);
          cc = mfma32(al, bh[ni], cc);
          acc[mi][ni] = cc;
        }
      }
      __builtin_amdgcn_s_setprio(0);
    }

    if (c + 1 < 16)
      asm volatile("s_waitcnt vmcnt(0)\n\ts_barrier" ::: "memory");
  }
#undef STAGE_A
#undef STAGE_B

  float* Cg = attn + (size_t)b * NQ_ * NKV_;
#pragma unroll
  for (int mi = 0; mi < 4; ++mi)
#pragma unroll
    for (int ni = 0; ni < 2; ++ni)
#pragma unroll
      for (int r = 0; r < 16; ++r) {
        const int row_g = brow + wr * 128 + mi * 32 + (r & 3) + 8 * (r >> 2) + 4 * half;
        const int col_g = bcol + wcn * 64 + ni * 32 + fr;
        Cg[(size_t)row_g * NKV_ + col_g] = acc[mi][ni][r];
      }
}

// ---------------------------------------------------------------------------
// PV GEMM: out[b,q,n] = sum_j attnb[b,q,j] * xT[b,n,j]. Both operands bf16,
// 32x32x16 MFMA, wave tile 64x64, same widened swizzle g(row) as score.
// Double-buffered 2-phase; single vmcnt(0) AFTER the MFMA cluster.
// ---------------------------------------------------------------------------
__global__ __launch_bounds__(256, 2)
void pv_gemm(const __bf16* __restrict__ attnb, const __bf16* __restrict__ xT,
             float* __restrict__ out)
{
  __shared__ __bf16 At[2][128 * 64];
  __shared__ __bf16 Bt[2][128 * 64];

  const int swz  = xcd_swz(blockIdx.x, gridDim.x);
  const int bx   = swz & 3;           // DIN block
  const int by   = (swz >> 2) & 15;   // NQ block
  const int b    = swz >> 6;          // batch

  const int t    = threadIdx.x;
  const int lane = t & 63;
  const int w    = t >> 6;
  const int wr   = w >> 1;
  const int wc   = w & 1;
  const int brow = by * 128;   // q rows
  const int bcol = bx * 128;   // din cols
  const int fr   = lane & 31;
  const int half = lane >> 5;
  const int gg   = (fr & 7) ^ (((fr >> 3) & 1) << 2);

  const int srow = t >> 3;
  const int sig  = (t & 7) ^ ((t >> 3) & 7) ^ (((t >> 6) & 1) << 2);
  const __bf16* aG = attnb + ((size_t)b * NQ_ + brow + srow) * NKV_ + sig * 8;
  const __bf16* bG = xT + (size_t)b * DIN_ * NKV_ + (size_t)(bcol + srow) * NKV_ + sig * 8;

  f32x16 acc[2][2] = {};

#define PV_STAGE(ks, buf) do { \
    const __bf16* a_ = aG + (size_t)(ks) * 64; \
    const __bf16* b_ = bG + (size_t)(ks) * 64; \
    __bf16* al_ = At[buf] + w * 512; \
    __bf16* bl_ = Bt[buf] + w * 512; \
    _Pragma("unroll") for (int i = 0; i < 4; ++i) { \
      gload_lds16(a_ + (size_t)i * 32 * NKV_, al_ + i * 2048); \
      gload_lds16(b_ + (size_t)i * 32 * NKV_, bl_ + i * 2048); } } while (0)

  // prologue: stage chunk 0, drain, barrier.
  PV_STAGE(0, 0);
  asm volatile("s_waitcnt vmcnt(0)\n\ts_barrier" ::: "memory");

  for (int ks = 0; ks < NKV_ / 64; ++ks) {
    const int cur = ks & 1;
    if (ks + 1 < NKV_ / 64) PV_STAGE(ks + 1, cur ^ 1);

    const __bf16* Ac = At[cur];
    const __bf16* Bc = Bt[cur];
#pragma unroll
    for (int s = 0; s < 4; ++s) {                  // K=16 steps over K=64
      const int oS = ((s * 2 + half) ^ gg) * 8;
      bf16x8 bh[2];
#pragma unroll
      for (int ni = 0; ni < 2; ++ni)
        bh[ni] = *(const bf16x8*)&Bc[(wc * 64 + ni * 32 + fr) * 64 + oS];
      __builtin_amdgcn_s_setprio(1);
#pragma unroll
      for (int mi = 0; mi < 2; ++mi) {
        const bf16x8 ah = *(const bf16x8*)&Ac[(wr * 64 + mi * 32 + fr) * 64 + oS];
#pragma unroll
        for (int ni = 0; ni < 2; ++ni)
          acc[mi][ni] = mfma32(ah, bh[ni], acc[mi][ni]);
      }
      __builtin_amdgcn_s_setprio(0);
    }
    asm volatile("s_waitcnt vmcnt(0)\n\ts_barrier" ::: "memory");
  }
#undef PV_STAGE

  float* Cg = out + (size_t)b * NQ_ * DIN_;
#pragma unroll
  for (int mi = 0; mi < 2; ++mi)
#pragma unroll
    for (int ni = 0; ni < 2; ++ni)
#pragma unroll
      for (int r = 0; r < 16; ++r) {
        const int row_g = brow + wr * 64 + mi * 32 + (r & 3) + 8 * (r >> 2) + 4 * half;
        const int col_g = bcol + wc * 64 + ni * 32 + fr;
        Cg[(size_t)row_g * DIN_ + col_g] = acc[mi][ni][r];
      }
}

// ---------------------------------------------------------------------------
// x [B, NKV, DIN] fp32 -> xT [B, DIN, NKV] bf16
// ---------------------------------------------------------------------------
__global__ void transpose_x(const float* __restrict__ x, __bf16* __restrict__ xT)
{
  __shared__ float tile[32][33];
  const int b  = blockIdx.z;
  const int j0 = blockIdx.x * 32;   // NKV index
  const int i0 = blockIdx.y * 32;   // DIN index
  const float* xs = x  + (size_t)b * NKV_ * DIN_;
  __bf16*      xd = xT + (size_t)b * DIN_ * NKV_;
  const int tx = threadIdx.x, ty = threadIdx.y;  // 32 x 8
#pragma unroll
  for (int p = 0; p < 32; p += 8)
    tile[ty + p][tx] = xs[(size_t)(j0 + ty + p) * DIN_ + i0 + tx];
  __syncthreads();
#pragma unroll
  for (int p = 0; p < 32; p += 8)
    xd[(size_t)(i0 + ty + p) * NKV_ + j0 + tx] = (__bf16)tile[tx][ty + p];
}

// ---------------------------------------------------------------------------
// In-place row softmax over attn [rows x 2048]; also writes bf16 copy.
// ---------------------------------------------------------------------------
__global__ void softmax_rows(float* __restrict__ attn, __bf16* __restrict__ attnb)
{
  const int lane = threadIdx.x & 63;
  const int wv   = threadIdx.x >> 6;
  const size_t row = (size_t)blockIdx.x * 4 + wv;
  float*  p  = attn  + row * NKV_;
  __bf16* pb = attnb + row * NKV_;

  float4 v[8];
  float mx = -1e30f;
#pragma unroll
  for (int i = 0; i < 8; ++i) {
    v[i] = *(const float4*)&p[i * 256 + lane * 4];
    mx = fmaxf(mx, fmaxf(fmaxf(v[i].x, v[i].y), fmaxf(v[i].z, v[i].w)));
  }
#pragma unroll
  for (int off = 32; off; off >>= 1) mx = fmaxf(mx, __shfl_xor(mx, off, 64));

  float sum = 0.f;
#pragma unroll
  for (int i = 0; i < 8; ++i) {
    v[i].x = expf(v[i].x - mx);
    v[i].y = expf(v[i].y - mx);
    v[i].z = expf(v[i].z - mx);
    v[i].w = expf(v[i].w - mx);
    sum += v[i].x + v[i].y + v[i].z + v[i].w;
  }
#pragma unroll
  for (int off = 32; off; off >>= 1) sum += __shfl_xor(sum, off, 64);

  const float inv = 1.0f / sum;
#pragma unroll
  for (int i = 0; i < 8; ++i) {
    v[i].x *= inv; v[i].y *= inv; v[i].z *= inv; v[i].w *= inv;
    *(float4*)&p[i * 256 + lane * 4] = v[i];
    bf16x4 hv;
    hv[0] = (__bf16)v[i].x; hv[1] = (__bf16)v[i].y;
    hv[2] = (__bf16)v[i].z; hv[3] = (__bf16)v[i].w;
    *(bf16x4*)&pb[i * 256 + lane * 4] = hv;
  }
}

// ---------------------------------------------------------------------------
extern "C" void kernel_launch(void* const* d_in, const int* in_sizes, int n_in,
                              void* d_out, int out_size, void* d_ws, size_t ws_size,
                              hipStream_t stream)
{
  (void)in_sizes; (void)n_in; (void)out_size; (void)ws_size;
  const float* query  = (const float*)d_in[0];  // [8, 2048, 512]
  const float* key    = (const float*)d_in[1];  // [2048, 512]
  const float* x      = (const float*)d_in[2];  // [8, 2048, 512]
  const float* W_proj = (const float*)d_in[3];  // [512, 512]
  const float* b_proj = (const float*)d_in[4];  // [512]
  const float* W_px   = (const float*)d_in[5];  // [512, 512]
  const float* b_px   = (const float*)d_in[6];  // [512]

  float* out  = (float*)d_out;                          // [8, 2048, 512]
  float* attn = out + (size_t)B_ * NQ_ * DIN_;          // [8, 2048, 2048]

  const size_t PQE = (size_t)B_ * NQ_ * DQ_;            // 8.39M elements
  __bf16* qph = (__bf16*)d_ws;
  __bf16* qpl = qph + PQE;
  __bf16* kmh = qpl + PQE;
  __bf16* kml = kmh + PQE;
  __bf16* xT  = kml + PQE;                              // [8, 512, 2048] bf16
  // after score_gemm, qp/km are dead: reuse their 4*PQE bf16 region (=67.1MB)
  // for the bf16 attn copy (8*2048*2048 = 4*PQE elements exactly).
  __bf16* attnb = qph;

  // allow 128 KiB dynamic LDS for score_gemm (idempotent, capture-safe)
  hipFuncSetAttribute((const void*)score_gemm,
                      hipFuncAttributeMaxDynamicSharedMemorySize, 131072);

  // x^T (bf16) for the PV GEMM B-operand
  transpose_x<<<dim3(NKV_ / 32, DIN_ / 32, B_), dim3(32, 8), 0, stream>>>(x, xT);

  // q_proj = query @ W_proj^T + b_proj  -> split bf16
  proj_gemm<1><<<dim3(DQ_ / 128, (B_ * NQ_) / 128, 1), 256, 0, stream>>>(
      query, W_proj, qph, qpl, b_proj, nullptr);

  // k = x @ W_px^T + b_px + key        -> split bf16
  proj_gemm<2><<<dim3(DQ_ / 128, (B_ * NQ_) / 128, 1), 256, 0, stream>>>(
      x, W_px, kmh, kml, b_px, key);

  // raw scores into attn region of d_out (256^2 tiles, XCD-swizzled)
  score_gemm<<<(NKV_ / 256) * (NQ_ / 256) * B_, 512, 131072, stream>>>(
      qph, qpl, kmh, kml, attn);

  // softmax rows in place + bf16 copy into ws
  softmax_rows<<<(B_ * NQ_) / 4, 256, 0, stream>>>(attn, attnb);

  // out[b] = attn[b] @ x[b]  (1D grid, XCD-swizzled)
  pv_gemm<<<(DIN_ / 128) * (NQ_ / 128) * B_, 256, 0, stream>>>(attnb, xT, out);
}

// Round 11
// 225.112 us; speedup vs baseline: 1.3548x; 1.3504x over previous
//
#include <hip/hip_runtime.h>
#include <hip/hip_bf16.h>

// Problem constants
#define B_   8
#define NQ_  2048
#define NKV_ 2048
#define DQ_  512
#define DIN_ 512

using f32x4 = __attribute__((ext_vector_type(4))) float;
using f16   = _Float16;
using f16x4 = __attribute__((ext_vector_type(4))) _Float16;
using f16x8 = __attribute__((ext_vector_type(8))) _Float16;

__device__ __forceinline__ f32x4 mfma16f(f16x8 a, f16x8 b, f32x4 c) {
  return __builtin_amdgcn_mfma_f32_16x16x32_f16(a, b, c, 0, 0, 0);
}

// async global->LDS, 16B per lane. LDS dest is wave-uniform base (+lane*16 in HW).
__device__ __forceinline__ void gload_lds16(const void* g, void* l) {
  __builtin_amdgcn_global_load_lds(
      (const __attribute__((address_space(1))) void*)g,
      (__attribute__((address_space(3))) void*)l, 16, 0, 0);
}

// bijective XCD-aware remap (nwg % 8 == 0)
__device__ __forceinline__ int xcd_swz(int bid, int nwg) {
  const int c = nwg >> 3;
  return (bid & 7) * c + (bid >> 3);
}

// ---------------------------------------------------------------------------
// Projection GEMM: C[m,n] = sum_k A[m,k]*B[n,k] + bias[n] (+ key), fp32 in,
// fp16 out, SINGLE product (fp16 hi x hi; error ~3e-4 abs, fine for logits).
// T14 issue-early reg preload of next K-tile.
// EPI: 1 +bias[n]; 2 +bias[n] + key[(m&2047)*512+n]
// ---------------------------------------------------------------------------
template<int EPI>
__global__ __launch_bounds__(256, 2)
void proj_gemm(const float* __restrict__ A, const float* __restrict__ Bm,
               f16* __restrict__ C,
               const float* __restrict__ bias, const float* __restrict__ keyp)
{
  constexpr int PAD = 8;
  __shared__ f16 Ah[128][64 + PAD];
  __shared__ f16 Bh[128][64 + PAD];

  const int tid  = threadIdx.x;
  const int lane = tid & 63;
  const int w    = tid >> 6;
  const int wr   = w >> 1;
  const int wc   = w & 1;
  const int brow = blockIdx.y * 128;
  const int bcol = blockIdx.x * 128;

  const float* Ag = A  + (size_t)brow * DQ_;
  const float* Bg = Bm + (size_t)bcol * DQ_;

  f32x4 acc[4][4] = {};

  const int sr = tid >> 4;
  const int sc = (tid & 15) * 4;

  float4 pa[8], pb[8];
#pragma unroll
  for (int p = 0; p < 8; ++p) {
    pa[p] = *(const float4*)(Ag + (size_t)(p * 16 + sr) * DQ_ + sc);
    pb[p] = *(const float4*)(Bg + (size_t)(p * 16 + sr) * DQ_ + sc);
  }

  for (int k0 = 0; k0 < DQ_; k0 += 64) {
    __syncthreads();
#pragma unroll
    for (int p = 0; p < 8; ++p) {
      const int r = p * 16 + sr;
      f16x4 ha, hb;
      ha[0] = (f16)pa[p].x; ha[1] = (f16)pa[p].y;
      ha[2] = (f16)pa[p].z; ha[3] = (f16)pa[p].w;
      hb[0] = (f16)pb[p].x; hb[1] = (f16)pb[p].y;
      hb[2] = (f16)pb[p].z; hb[3] = (f16)pb[p].w;
      *(f16x4*)&Ah[r][sc] = ha;
      *(f16x4*)&Bh[r][sc] = hb;
    }
    if (k0 + 64 < DQ_) {
#pragma unroll
      for (int p = 0; p < 8; ++p) {
        pa[p] = *(const float4*)(Ag + (size_t)(p * 16 + sr) * DQ_ + k0 + 64 + sc);
        pb[p] = *(const float4*)(Bg + (size_t)(p * 16 + sr) * DQ_ + k0 + 64 + sc);
      }
    }
    __syncthreads();
#pragma unroll
    for (int kk = 0; kk < 2; ++kk) {
      const int fr = lane & 15;
      const int fc = kk * 32 + (lane >> 4) * 8;
      f16x8 ah[4], bh[4];
#pragma unroll
      for (int m = 0; m < 4; ++m)
        ah[m] = *(const f16x8*)&Ah[wr * 64 + m * 16 + fr][fc];
#pragma unroll
      for (int n = 0; n < 4; ++n)
        bh[n] = *(const f16x8*)&Bh[wc * 64 + n * 16 + fr][fc];
#pragma unroll
      for (int m = 0; m < 4; ++m)
#pragma unroll
        for (int n = 0; n < 4; ++n)
          acc[m][n] = mfma16f(ah[m], bh[n], acc[m][n]);
    }
  }

#pragma unroll
  for (int m = 0; m < 4; ++m)
#pragma unroll
    for (int n = 0; n < 4; ++n)
#pragma unroll
      for (int r = 0; r < 4; ++r) {
        const int row_g = brow + wr * 64 + m * 16 + (lane >> 4) * 4 + r;
        const int col_g = bcol + wc * 64 + n * 16 + (lane & 15);
        float vv = acc[m][n][r] + bias[col_g];
        if (EPI == 2) vv += keyp[(size_t)(row_g & (NKV_ - 1)) * DQ_ + col_g];
        C[(size_t)row_g * DQ_ + col_g] = (f16)vv;
      }
}

// ---------------------------------------------------------------------------
// Score GEMM: attn_raw = qp . km^T, pure fp16 single product.
// 256x256 tile, 512 threads (8 waves), wave-owned 128x64 tiles (2Mx4N),
// 16x16x32_f16 MFMA. K-chunk = 32 (64B LDS rows, 4 16B slots, XOR slot
// swizzle ^(row&3) -- proven-zero-conflict 16-row/4-slot read shape).
// Double-buffered 64KB static LDS; one vmcnt(0)+s_barrier per chunk.
// Per chunk/wave: 12 ds_read_b128, 32 MFMA.
// ---------------------------------------------------------------------------
__global__ __launch_bounds__(512, 2)
void score_gemm(const f16* __restrict__ qp, const f16* __restrict__ km,
                float* __restrict__ attn)
{
  __shared__ f16 ABuf[2 * 8192];   // [parity][256 rows][32]
  __shared__ f16 BBuf[2 * 8192];

  const int swz  = xcd_swz(blockIdx.x, gridDim.x);   // 512 blocks
  const int bx   = swz & 7;           // NKV block (256)
  const int by   = (swz >> 3) & 7;    // NQ block (256)
  const int b    = swz >> 6;          // batch

  const int t    = threadIdx.x;       // 0..511
  const int lane = t & 63;
  const int w    = t >> 6;            // 0..7
  const int wr   = w >> 2;            // 0..1 (M: rows wr*128..+128)
  const int wcn  = w & 3;             // 0..3 (N: cols wcn*64..+64)
  const int brow = by * 256;
  const int bcol = bx * 256;
  const int fr   = lane & 15;
  const int q    = lane >> 4;
  const int slotE = ((q ^ (fr & 3)) * 8);   // element offset within 32-elem row

  // staging: thread t -> row srow = t>>2 (0..127; +128 for issue 1),
  // phys slot t&3, logical sig = (t&3)^(srow&3).
  const int srow = t >> 2;
  const int sig  = (t & 3) ^ (srow & 3);
  const f16* aG = qp + ((size_t)b * NQ_  + brow + srow) * DQ_ + sig * 8;
  const f16* bG = km + ((size_t)b * NKV_ + bcol + srow) * DQ_ + sig * 8;

#define STAGE_A(kc) do { \
    const f16* s_ = aG + (kc) * 32; \
    f16* d_ = ABuf + ((kc) & 1) * 8192 + w * 512; \
    gload_lds16(s_, d_); \
    gload_lds16(s_ + (size_t)128 * DQ_, d_ + 4096); } while (0)
#define STAGE_B(kc) do { \
    const f16* s_ = bG + (kc) * 32; \
    f16* d_ = BBuf + ((kc) & 1) * 8192 + w * 512; \
    gload_lds16(s_, d_); \
    gload_lds16(s_ + (size_t)128 * DQ_, d_ + 4096); } while (0)

  f32x4 acc[8][4] = {};   // wave-owned 128x64: 8 m-frags x 4 n-frags

  STAGE_A(0); STAGE_B(0);
  asm volatile("s_waitcnt vmcnt(0)\n\ts_barrier" ::: "memory");

  for (int c = 0; c < 16; ++c) {
    if (c + 1 < 16) { STAGE_A(c + 1); STAGE_B(c + 1); }

    const f16* Ab = ABuf + (c & 1) * 8192;
    const f16* Bb = BBuf + (c & 1) * 8192;

    f16x8 bh[4];
#pragma unroll
    for (int ni = 0; ni < 4; ++ni)
      bh[ni] = *(const f16x8*)&Bb[(wcn * 64 + ni * 16 + fr) * 32 + slotE];

    __builtin_amdgcn_s_setprio(1);
#pragma unroll
    for (int mi = 0; mi < 8; ++mi) {
      const f16x8 ah = *(const f16x8*)&Ab[(wr * 128 + mi * 16 + fr) * 32 + slotE];
#pragma unroll
      for (int ni = 0; ni < 4; ++ni)
        acc[mi][ni] = mfma16f(ah, bh[ni], acc[mi][ni]);
    }
    __builtin_amdgcn_s_setprio(0);

    if (c + 1 < 16)
      asm volatile("s_waitcnt vmcnt(0)\n\ts_barrier" ::: "memory");
  }
#undef STAGE_A
#undef STAGE_B

  float* Cg = attn + (size_t)b * NQ_ * NKV_;
#pragma unroll
  for (int mi = 0; mi < 8; ++mi)
#pragma unroll
    for (int ni = 0; ni < 4; ++ni)
#pragma unroll
      for (int r = 0; r < 4; ++r) {
        const int row_g = brow + wr * 128 + mi * 16 + q * 4 + r;
        const int col_g = bcol + wcn * 64 + ni * 16 + fr;
        Cg[(size_t)row_g * NKV_ + col_g] = acc[mi][ni][r];
      }
}

// ---------------------------------------------------------------------------
// PV GEMM: out[b,q,n] = sum_j attnb[b,q,j] * xT[b,n,j]. fp16 operands,
// double-buffered 2-phase (proven R8 structure, 128B rows, 8 slots, 0 confl).
// ---------------------------------------------------------------------------
__global__ __launch_bounds__(256, 2)
void pv_gemm(const f16* __restrict__ attnb, const f16* __restrict__ xT,
             float* __restrict__ out)
{
  __shared__ f16 At[2][128 * 64];
  __shared__ f16 Bt[2][128 * 64];

  const int swz  = xcd_swz(blockIdx.x, gridDim.x);
  const int bx   = swz & 3;           // DIN block
  const int by   = (swz >> 2) & 15;   // NQ block
  const int b    = swz >> 6;          // batch

  const int t    = threadIdx.x;
  const int lane = t & 63;
  const int w    = t >> 6;
  const int wr   = w >> 1;
  const int wc   = w & 1;
  const int brow = by * 128;   // q rows
  const int bcol = bx * 128;   // din cols

  const int srow  = t >> 3;
  const int sslot = t & 7;
  const int sig   = sslot ^ (srow & 7);
  const f16* aG = attnb + ((size_t)b * NQ_ + brow + srow) * NKV_ + sig * 8;
  const f16* bG = xT + (size_t)b * DIN_ * NKV_ + (size_t)(bcol + srow) * NKV_ + sig * 8;

  f32x4 acc[4][4] = {};
  const int fr = lane & 15;
  const int q  = lane >> 4;

#define PV_STAGE(ks, buf) do { \
    const f16* a_ = aG + (size_t)(ks) * 64; \
    const f16* b_ = bG + (size_t)(ks) * 64; \
    f16* al_ = At[buf] + w * 512; \
    f16* bl_ = Bt[buf] + w * 512; \
    _Pragma("unroll") for (int i = 0; i < 4; ++i) { \
      gload_lds16(a_ + (size_t)i * 32 * NKV_, al_ + i * 2048); \
      gload_lds16(b_ + (size_t)i * 32 * NKV_, bl_ + i * 2048); } } while (0)

  PV_STAGE(0, 0);
  asm volatile("s_waitcnt vmcnt(0)\n\ts_barrier" ::: "memory");

  for (int ks = 0; ks < NKV_ / 64; ++ks) {
    const int cur = ks & 1;
    if (ks + 1 < NKV_ / 64) PV_STAGE(ks + 1, cur ^ 1);

    const f16* Ac = At[cur];
    const f16* Bc = Bt[cur];
#pragma unroll
    for (int kk = 0; kk < 2; ++kk) {
      f16x8 ah[4], bh[4];
#pragma unroll
      for (int m = 0; m < 4; ++m) {
        const int rt = wr * 64 + m * 16 + fr;
        ah[m] = *(const f16x8*)&Ac[rt * 64 + (((kk * 4 + q) ^ (rt & 7)) * 8)];
      }
#pragma unroll
      for (int n = 0; n < 4; ++n) {
        const int rt = wc * 64 + n * 16 + fr;
        bh[n] = *(const f16x8*)&Bc[rt * 64 + (((kk * 4 + q) ^ (rt & 7)) * 8)];
      }
#pragma unroll
      for (int m = 0; m < 4; ++m)
#pragma unroll
        for (int n = 0; n < 4; ++n)
          acc[m][n] = mfma16f(ah[m], bh[n], acc[m][n]);
    }
    asm volatile("s_waitcnt vmcnt(0)\n\ts_barrier" ::: "memory");
  }
#undef PV_STAGE

  float* Cg = out + (size_t)b * NQ_ * DIN_;
#pragma unroll
  for (int m = 0; m < 4; ++m)
#pragma unroll
    for (int n = 0; n < 4; ++n)
#pragma unroll
      for (int r = 0; r < 4; ++r) {
        const int row_g = brow + wr * 64 + m * 16 + q * 4 + r;
        const int col_g = bcol + wc * 64 + n * 16 + fr;
        Cg[(size_t)row_g * DIN_ + col_g] = acc[m][n][r];
      }
}

// ---------------------------------------------------------------------------
// x [B, NKV, DIN] fp32 -> xT [B, DIN, NKV] fp16
// ---------------------------------------------------------------------------
__global__ void transpose_x(const float* __restrict__ x, f16* __restrict__ xT)
{
  __shared__ float tile[32][33];
  const int b  = blockIdx.z;
  const int j0 = blockIdx.x * 32;   // NKV index
  const int i0 = blockIdx.y * 32;   // DIN index
  const float* xs = x  + (size_t)b * NKV_ * DIN_;
  f16*         xd = xT + (size_t)b * DIN_ * NKV_;
  const int tx = threadIdx.x, ty = threadIdx.y;  // 32 x 8
#pragma unroll
  for (int p = 0; p < 32; p += 8)
    tile[ty + p][tx] = xs[(size_t)(j0 + ty + p) * DIN_ + i0 + tx];
  __syncthreads();
#pragma unroll
  for (int p = 0; p < 32; p += 8)
    xd[(size_t)(i0 + ty + p) * NKV_ + j0 + tx] = (f16)tile[tx][ty + p];
}

// ---------------------------------------------------------------------------
// In-place row softmax over attn [rows x 2048]; also writes fp16 copy.
// ---------------------------------------------------------------------------
__global__ void softmax_rows(float* __restrict__ attn, f16* __restrict__ attnb)
{
  const int lane = threadIdx.x & 63;
  const int wv   = threadIdx.x >> 6;
  const size_t row = (size_t)blockIdx.x * 4 + wv;
  float* p  = attn  + row * NKV_;
  f16*   pb = attnb + row * NKV_;

  float4 v[8];
  float mx = -1e30f;
#pragma unroll
  for (int i = 0; i < 8; ++i) {
    v[i] = *(const float4*)&p[i * 256 + lane * 4];
    mx = fmaxf(mx, fmaxf(fmaxf(v[i].x, v[i].y), fmaxf(v[i].z, v[i].w)));
  }
#pragma unroll
  for (int off = 32; off; off >>= 1) mx = fmaxf(mx, __shfl_xor(mx, off, 64));

  float sum = 0.f;
#pragma unroll
  for (int i = 0; i < 8; ++i) {
    v[i].x = expf(v[i].x - mx);
    v[i].y = expf(v[i].y - mx);
    v[i].z = expf(v[i].z - mx);
    v[i].w = expf(v[i].w - mx);
    sum += v[i].x + v[i].y + v[i].z + v[i].w;
  }
#pragma unroll
  for (int off = 32; off; off >>= 1) sum += __shfl_xor(sum, off, 64);

  const float inv = 1.0f / sum;
#pragma unroll
  for (int i = 0; i < 8; ++i) {
    v[i].x *= inv; v[i].y *= inv; v[i].z *= inv; v[i].w *= inv;
    *(float4*)&p[i * 256 + lane * 4] = v[i];
    f16x4 hv;
    hv[0] = (f16)v[i].x; hv[1] = (f16)v[i].y;
    hv[2] = (f16)v[i].z; hv[3] = (f16)v[i].w;
    *(f16x4*)&pb[i * 256 + lane * 4] = hv;
  }
}

// ---------------------------------------------------------------------------
extern "C" void kernel_launch(void* const* d_in, const int* in_sizes, int n_in,
                              void* d_out, int out_size, void* d_ws, size_t ws_size,
                              hipStream_t stream)
{
  (void)in_sizes; (void)n_in; (void)out_size; (void)ws_size;
  const float* query  = (const float*)d_in[0];  // [8, 2048, 512]
  const float* key    = (const float*)d_in[1];  // [2048, 512]
  const float* x      = (const float*)d_in[2];  // [8, 2048, 512]
  const float* W_proj = (const float*)d_in[3];  // [512, 512]
  const float* b_proj = (const float*)d_in[4];  // [512]
  const float* W_px   = (const float*)d_in[5];  // [512, 512]
  const float* b_px   = (const float*)d_in[6];  // [512]

  float* out  = (float*)d_out;                          // [8, 2048, 512]
  float* attn = out + (size_t)B_ * NQ_ * DIN_;          // [8, 2048, 2048]

  const size_t PQE = (size_t)B_ * NQ_ * DQ_;            // 8.39M elements
  // ws layout (fp16): [xT | qp | km | ...]; after score, qp/km are dead and
  // attnb (4*PQE elems) starts at qp, extending 2*PQE past km into free ws.
  // Total ws use = 5*PQE*2B = 83.9 MB (<= 100.7 MB proven in R1).
  f16* xT = (f16*)d_ws;           // [8, 512, 2048]
  f16* qp = xT + PQE;             // [16384, 512]
  f16* km = qp + PQE;             // [16384, 512]
  f16* attnb = qp;                // [8, 2048, 2048] fp16 (reuses qp/km + free)

  // x^T (fp16) for the PV GEMM B-operand
  transpose_x<<<dim3(NKV_ / 32, DIN_ / 32, B_), dim3(32, 8), 0, stream>>>(x, xT);

  // q_proj = query @ W_proj^T + b_proj  -> fp16
  proj_gemm<1><<<dim3(DQ_ / 128, (B_ * NQ_) / 128, 1), 256, 0, stream>>>(
      query, W_proj, qp, b_proj, nullptr);

  // k = x @ W_px^T + b_px + key        -> fp16
  proj_gemm<2><<<dim3(DQ_ / 128, (B_ * NQ_) / 128, 1), 256, 0, stream>>>(
      x, W_px, km, b_px, key);

  // raw scores into attn region of d_out (256^2 tiles, XCD-swizzled)
  score_gemm<<<(NKV_ / 256) * (NQ_ / 256) * B_, 512, 0, stream>>>(qp, km, attn);

  // softmax rows in place + fp16 copy into ws
  softmax_rows<<<(B_ * NQ_) / 4, 256, 0, stream>>>(attn, attnb);

  // out[b] = attn[b] @ x[b]  (1D grid, XCD-swizzled)
  pv_gemm<<<(DIN_ / 128) * (NQ_ / 128) * B_, 256, 0, stream>>>(attnb, xT, out);
}